// Round 1
// baseline (529.579 us; speedup 1.0000x reference)
//
#include <hip/hip_runtime.h>
#include <cstdint>

#define L_SEQ 2304
#define CDIM  512
#define NHEADS 8
#define HD    64
#define LL    ((size_t)L_SEQ * L_SEQ)

typedef short  s8v  __attribute__((ext_vector_type(8)));
typedef float  f4v  __attribute__((ext_vector_type(4)));

__device__ __forceinline__ ushort f2bf(float f) {
    union { float f; uint32_t u; } v; v.f = f;
    uint32_t u = v.u;
    uint32_t r = (u + 0x7FFFu + ((u >> 16) & 1u)) >> 16;
    return (ushort)r;
}

// ==================================================================
// QKV projection -> bf16 outputs. q,k in (b,h,l,d); v transposed (b,h,d,l).
// Q pre-scaled by 0.125 (exact pow2). grid (36, 8, 6), block 256.
__global__ __launch_bounds__(256) void qkv_gemm(
    const float* __restrict__ x, const float* __restrict__ pos,
    const float* __restrict__ Wq, const float* __restrict__ bq,
    const float* __restrict__ Wk, const float* __restrict__ bk,
    const float* __restrict__ Wv, const float* __restrict__ bv,
    ushort* __restrict__ q_t, ushort* __restrict__ k_t, ushort* __restrict__ v_t)
{
    const int l0 = blockIdx.x * 64;
    const int o0 = blockIdx.y * 64;
    const int b  = blockIdx.z / 3;
    const int w  = blockIdx.z % 3;
    const float* W    = (w == 0) ? Wq : (w == 1) ? Wk : Wv;
    const float* bias = (w == 0) ? bq : (w == 1) ? bk : bv;

    __shared__ float As[16][68];
    __shared__ float Xs[16][68];

    const int t  = threadIdx.x;
    const int ti = t & 15;
    const int tj = t >> 4;
    float acc[4][4] = {};

    const float* xb = x + (size_t)b * CDIM * L_SEQ;

    for (int c0 = 0; c0 < CDIM; c0 += 16) {
        {
            const int oi = t >> 2;
            const int cc = (t & 3) * 4;
            const float4 wv = *(const float4*)&W[(size_t)(o0 + oi) * CDIM + c0 + cc];
            As[cc + 0][oi] = wv.x;
            As[cc + 1][oi] = wv.y;
            As[cc + 2][oi] = wv.z;
            As[cc + 3][oi] = wv.w;
        }
        {
            const int kk = t >> 4;
            const int j  = (t & 15) * 4;
            const size_t off = (size_t)(c0 + kk) * L_SEQ + l0 + j;
            float4 xv = *(const float4*)&xb[off];
            const float4 pv = *(const float4*)&pos[off];
            xv.x += pv.x; xv.y += pv.y; xv.z += pv.z; xv.w += pv.w;
            *(float4*)&Xs[kk][j] = xv;
        }
        __syncthreads();
        #pragma unroll
        for (int kk = 0; kk < 16; kk++) {
            const float4 a  = *(const float4*)&As[kk][ti * 4];
            const float4 bb = *(const float4*)&Xs[kk][tj * 4];
            const float av[4] = {a.x, a.y, a.z, a.w};
            const float bv4[4] = {bb.x, bb.y, bb.z, bb.w};
            #pragma unroll
            for (int i = 0; i < 4; i++)
                #pragma unroll
                for (int j = 0; j < 4; j++)
                    acc[i][j] += av[i] * bv4[j];
        }
        __syncthreads();
    }

    const int h = o0 >> 6;
    const float4 bi = *(const float4*)&bias[o0 + ti * 4];
    const float bia[4] = {bi.x, bi.y, bi.z, bi.w};

    if (w < 2) {
        // q/k row-major (b,h,l,d), Q scaled by 0.125
        const float sc = (w == 0) ? 0.125f : 1.0f;
        ushort* op = (w == 0 ? q_t : k_t) + ((size_t)b * NHEADS + h) * L_SEQ * HD;
        #pragma unroll
        for (int j = 0; j < 4; j++) {
            const int l = l0 + tj * 4 + j;
            ushort4 st;
            st.x = f2bf((acc[0][j] + bia[0]) * sc);
            st.y = f2bf((acc[1][j] + bia[1]) * sc);
            st.z = f2bf((acc[2][j] + bia[2]) * sc);
            st.w = f2bf((acc[3][j] + bia[3]) * sc);
            *(ushort4*)&op[(size_t)l * HD + ti * 4] = st;
        }
    } else {
        // v transposed (b,h,d,l)
        ushort* op = v_t + ((size_t)b * NHEADS + h) * HD * L_SEQ;
        #pragma unroll
        for (int i = 0; i < 4; i++) {
            const int d = ti * 4 + i;
            ushort4 st;
            st.x = f2bf(acc[i][0] + bia[i]);
            st.y = f2bf(acc[i][1] + bia[i]);
            st.z = f2bf(acc[i][2] + bia[i]);
            st.w = f2bf(acc[i][3] + bia[i]);
            *(ushort4*)&op[(size_t)d * L_SEQ + l0 + tj * 4] = st;
        }
    }
}

// ==================================================================
// MFMA flash attention, intra-block split-K (flash-decoding style).
// Block = 512 threads (8 waves). Waves 0-3: q-rows [l0+wr*16,+16) x keys
// [0,1152). Waves 4-7: SAME q-rows x keys [1152,2304). Separate K/V LDS
// staging per key-half; partial (O,m,l) merged through LDS at the end.
// Doubles wave-parallelism (2304 -> 4608 waves) to lift the grid-limited
// 28% occupancy cap. grid 576 (1D, XCD-pinned head), block 512.
__global__ __launch_bounds__(512) void flash_attn_mfma(
    const ushort* __restrict__ q, const ushort* __restrict__ k,
    const ushort* __restrict__ vt, const int* __restrict__ mask,
    const float* __restrict__ rel_table, float* __restrict__ attn_out)
{
    __shared__ __align__(16) ushort Kf[2][512 * 8];   // B-frags for S, per key-half
    __shared__ __align__(16) ushort Vf[2][512 * 8];   // B-frags for PV, per key-half
    __shared__ __align__(16) ushort Pb[8][16 * 72];   // per-wave P, row-major [16][72]
    __shared__ float rt[65];
    __shared__ float Mex[4][16];                      // upper-half running max
    __shared__ float Lex[4][16];                      // upper-half running sum

    const int t    = threadIdx.x;
    const int id   = blockIdx.x;
    const int h    = id & 7;            // XCD-pinned head
    const int slot = id >> 3;
    const int b    = slot & 1;          // adjacent slots share mask rows (L2 reuse)
    const int qb   = slot >> 1;
    const int bh   = b * NHEADS + h;
    const int l0   = qb * 64;
    const int w    = t >> 6;
    const int lane = t & 63;
    const int n16  = lane & 15;
    const int q4   = lane >> 4;
    const int wr   = w & 3;             // row group within block
    const int half = w >> 2;            // key half: 0 -> [0,1152), 1 -> [1152,2304)

    if (t < 65) rt[t] = rel_table[h * 65 + t];

    const ushort* qp = q  + (size_t)bh * L_SEQ * HD;
    const ushort* kp = k  + (size_t)bh * L_SEQ * HD;
    const ushort* vp = vt + (size_t)bh * HD * L_SEQ;
    const int*    mp = mask + (size_t)h * LL;

    // Q A-fragments: A[m=lane&15][k=quad*8+j], rows l0+wr*16+n16
    const int qrow = l0 + wr * 16 + n16;
    const s8v qA0 = *(const s8v*)&qp[(size_t)qrow * HD + q4 * 8];
    const s8v qA1 = *(const s8v*)&qp[(size_t)qrow * HD + 32 + q4 * 8];

    f4v O[4] = {{0.f,0.f,0.f,0.f},{0.f,0.f,0.f,0.f},{0.f,0.f,0.f,0.f},{0.f,0.f,0.f,0.f}};
    float mrun[4] = {-3e38f, -3e38f, -3e38f, -3e38f};
    float lrun[4] = {0.f, 0.f, 0.f, 0.f};

    // staging decode: 2048 chunks (2 halves x (K 512 + V 512)), 4 per thread.
    // c = t + cc*512 in [0,1024): sH = key-half buffer, sC = chunk in buffer.
    int sH[2], sC[2], sKey[2], sD0[2];
    #pragma unroll
    for (int cc = 0; cc < 2; cc++) {
        const int c  = t + cc * 512;
        sH[cc] = c >> 9;
        const int c3 = c & 511;
        sC[cc] = c3;
        const int g = c3 >> 6;
        sKey[cc] = (g >> 1) * 16 + (c3 & 15);
        sD0[cc]  = (g & 1) * 32 + ((c3 >> 4) & 3) * 8;
    }

    const int rowbase = l0 + wr * 16 + q4 * 4;   // +r gives the C-layout row
    const ushort* Kh = Kf[half];
    const ushort* Vh = Vf[half];
    const int kbase = half * 1152;

    for (int mt = 0; mt < 18; mt++) {
        __syncthreads();   // WAR: previous tile's reads done before restage
        #pragma unroll
        for (int cc = 0; cc < 2; cc++) {
            const int mbs = sH[cc] * 1152 + mt * 64;
            *(s8v*)&Kf[sH[cc]][sC[cc] * 8] =
                *(const s8v*)&kp[(size_t)(mbs + sKey[cc]) * HD + sD0[cc]];
            // V chunk: V[d = sKey][keys mbs + sD0 .. +8]
            *(s8v*)&Vf[sH[cc]][sC[cc] * 8] =
                *(const s8v*)&vp[(size_t)sKey[cc] * L_SEQ + mbs + sD0[cc]];
        }
        __syncthreads();

        const int mb = kbase + mt * 64;

        // mask loads (issue early; int32 per harness bool convention)
        int mreg[4][4];
        #pragma unroll
        for (int t4 = 0; t4 < 4; t4++)
            #pragma unroll
            for (int r = 0; r < 4; r++)
                mreg[t4][r] = mp[(size_t)(rowbase + r) * L_SEQ + mb + t4 * 16 + n16];

        // S = Q K^T  (C layout: col=lane&15 -> key t4*16+n16, row=q4*4+r)
        f4v S[4];
        #pragma unroll
        for (int t4 = 0; t4 < 4; t4++) {
            const s8v b0 = *(const s8v*)&Kh[((t4 * 2 + 0) * 64 + lane) * 8];
            const s8v b1 = *(const s8v*)&Kh[((t4 * 2 + 1) * 64 + lane) * 8];
            f4v acc = {0.f, 0.f, 0.f, 0.f};
            acc = __builtin_amdgcn_mfma_f32_16x16x32_bf16(qA0, b0, acc, 0, 0, 0);
            acc = __builtin_amdgcn_mfma_f32_16x16x32_bf16(qA1, b1, acc, 0, 0, 0);
            S[t4] = acc;
        }

        // relative positional bias (then mask -> exactly -1e9, matching ref order)
        #pragma unroll
        for (int t4 = 0; t4 < 4; t4++) {
            const int A = (l0 + wr * 16) - (mb + t4 * 16);
            if (A >= 47) {
                const float bu = rt[64];
                #pragma unroll
                for (int r = 0; r < 4; r++) S[t4][r] += bu;
            } else if (A <= -47) {
                const float bu = rt[0];
                #pragma unroll
                for (int r = 0; r < 4; r++) S[t4][r] += bu;
            } else {
                #pragma unroll
                for (int r = 0; r < 4; r++) {
                    int dix = A + q4 * 4 + r - n16;
                    dix = min(max(dix, -32), 32) + 32;
                    S[t4][r] += rt[dix];
                }
            }
            #pragma unroll
            for (int r = 0; r < 4; r++)
                if (mreg[t4][r] == 0) S[t4][r] = -1e9f;
        }

        // online softmax per row (row stats replicated over 16 lanes of quad)
        float mx[4];
        #pragma unroll
        for (int r = 0; r < 4; r++) {
            float m0 = fmaxf(fmaxf(S[0][r], S[1][r]), fmaxf(S[2][r], S[3][r]));
            m0 = fmaxf(m0, __shfl_xor(m0, 1));
            m0 = fmaxf(m0, __shfl_xor(m0, 2));
            m0 = fmaxf(m0, __shfl_xor(m0, 4));
            m0 = fmaxf(m0, __shfl_xor(m0, 8));
            mx[r] = m0;
        }
        float al[4];
        #pragma unroll
        for (int r = 0; r < 4; r++) {
            const float mn = fmaxf(mrun[r], mx[r]);
            al[r] = __expf(mrun[r] - mn);
            mrun[r] = mn;
            float sum = 0.f;
            #pragma unroll
            for (int t4 = 0; t4 < 4; t4++) {
                const float p = __expf(S[t4][r] - mn);
                S[t4][r] = p;
                sum += p;
                Pb[w][(q4 * 4 + r) * 72 + t4 * 16 + n16] = f2bf(p);
            }
            sum += __shfl_xor(sum, 1);
            sum += __shfl_xor(sum, 2);
            sum += __shfl_xor(sum, 4);
            sum += __shfl_xor(sum, 8);
            lrun[r] = lrun[r] * al[r] + sum;
        }

        // rescale O, then O += P V   (per-wave Pb: same-wave dep, no barrier)
        const s8v pf0 = *(const s8v*)&Pb[w][n16 * 72 + q4 * 8];
        const s8v pf1 = *(const s8v*)&Pb[w][n16 * 72 + 32 + q4 * 8];
        #pragma unroll
        for (int t4 = 0; t4 < 4; t4++) {
            f4v o = O[t4];
            #pragma unroll
            for (int r = 0; r < 4; r++) o[r] *= al[r];
            const s8v v0 = *(const s8v*)&Vh[((t4 * 2 + 0) * 64 + lane) * 8];
            const s8v v1 = *(const s8v*)&Vh[((t4 * 2 + 1) * 64 + lane) * 8];
            o = __builtin_amdgcn_mfma_f32_16x16x32_bf16(pf0, v0, o, 0, 0, 0);
            o = __builtin_amdgcn_mfma_f32_16x16x32_bf16(pf1, v1, o, 0, 0, 0);
            O[t4] = o;
        }
    }

    // ---- merge the two key-halves through LDS (reuse Kf as fp32 O buffer) ----
    __syncthreads();                       // all waves done reading Kf/Vf
    float* Oex = (float*)Kf;               // 64 rows x 64 d x fp32 = 16 KB = sizeof(Kf)
    if (half == 1) {
        #pragma unroll
        for (int r = 0; r < 4; r++) {
            const int rr = q4 * 4 + r;
            #pragma unroll
            for (int t4 = 0; t4 < 4; t4++)
                Oex[(size_t)(wr * 16 + rr) * 64 + t4 * 16 + n16] = O[t4][r];
            if (n16 == 0) { Mex[wr][rr] = mrun[r]; Lex[wr][rr] = lrun[r]; }
        }
    }
    __syncthreads();
    if (half == 0) {
        float* op = attn_out + (size_t)bh * L_SEQ * HD;
        #pragma unroll
        for (int r = 0; r < 4; r++) {
            const int rr = q4 * 4 + r;
            const float m2 = Mex[wr][rr];
            const float l2 = Lex[wr][rr];
            const float M  = fmaxf(mrun[r], m2);
            const float a  = __expf(mrun[r] - M);
            const float bb = __expf(m2 - M);
            const float inv = 1.0f / (lrun[r] * a + l2 * bb);
            const float af = a * inv;
            const float bf = bb * inv;
            const size_t row = (size_t)(rowbase + r) * HD;
            #pragma unroll
            for (int t4 = 0; t4 < 4; t4++)
                op[row + t4 * 16 + n16] =
                    O[t4][r] * af + Oex[(size_t)(wr * 16 + rr) * 64 + t4 * 16 + n16] * bf;
        }
    }
}

// ==================================================================
// Output projection + bias + residual (fp32). grid (36, 8, 2), block 256.
__global__ __launch_bounds__(256) void out_gemm(
    const float* __restrict__ attn, const float* __restrict__ Wo,
    const float* __restrict__ bo, const float* __restrict__ x,
    float* __restrict__ y)
{
    const int l0 = blockIdx.x * 64;
    const int o0 = blockIdx.y * 64;
    const int b  = blockIdx.z;

    __shared__ float As[16][68];
    __shared__ float Xs[16][68];

    const int t  = threadIdx.x;
    const int ti = t & 15;
    const int tj = t >> 4;
    float acc[4][4] = {};

    const float* ab = attn + (size_t)b * NHEADS * L_SEQ * HD;

    for (int c0 = 0; c0 < CDIM; c0 += 16) {
        {
            const int oi = t >> 2;
            const int cc = (t & 3) * 4;
            const float4 wv = *(const float4*)&Wo[(size_t)(o0 + oi) * CDIM + c0 + cc];
            As[cc + 0][oi] = wv.x;
            As[cc + 1][oi] = wv.y;
            As[cc + 2][oi] = wv.z;
            As[cc + 3][oi] = wv.w;
        }
        {
            const int j   = t & 63;
            const int kkb = (t >> 6) * 4;
            const int c   = c0 + kkb;
            const int hh  = c >> 6;
            const int dd  = c & 63;
            const float4 av = *(const float4*)&ab[((size_t)hh * L_SEQ + l0 + j) * HD + dd];
            Xs[kkb + 0][j] = av.x;
            Xs[kkb + 1][j] = av.y;
            Xs[kkb + 2][j] = av.z;
            Xs[kkb + 3][j] = av.w;
        }
        __syncthreads();
        #pragma unroll
        for (int kk = 0; kk < 16; kk++) {
            const float4 a  = *(const float4*)&As[kk][ti * 4];
            const float4 bb = *(const float4*)&Xs[kk][tj * 4];
            const float av[4] = {a.x, a.y, a.z, a.w};
            const float bv4[4] = {bb.x, bb.y, bb.z, bb.w};
            #pragma unroll
            for (int i = 0; i < 4; i++)
                #pragma unroll
                for (int j = 0; j < 4; j++)
                    acc[i][j] += av[i] * bv4[j];
        }
        __syncthreads();
    }

    const float4 bi = *(const float4*)&bo[o0 + ti * 4];
    const float bia[4] = {bi.x, bi.y, bi.z, bi.w};
    #pragma unroll
    for (int i = 0; i < 4; i++) {
        const int o = o0 + ti * 4 + i;
        const size_t off = ((size_t)b * CDIM + o) * L_SEQ + l0 + tj * 4;
        const float4 xv = *(const float4*)&x[off];
        float4 st;
        st.x = acc[i][0] + bia[i] + xv.x;
        st.y = acc[i][1] + bia[i] + xv.y;
        st.z = acc[i][2] + bia[i] + xv.z;
        st.w = acc[i][3] + bia[i] + xv.w;
        *(float4*)&y[off] = st;
    }
}

// ==================================================================
__global__ __launch_bounds__(256) void ln_kernel(
    float* __restrict__ y, const float* __restrict__ gamma,
    const float* __restrict__ beta)
{
    const int t  = threadIdx.x;
    const int pi = t & 63;
    const int g  = t >> 6;
    const int pos = blockIdx.x * 64 + pi;
    const int b = (pos >= L_SEQ) ? 1 : 0;
    const int l = pos - b * L_SEQ;
    float* col = y + (size_t)b * CDIM * L_SEQ + l;

    float s = 0.f, sq = 0.f;
    for (int c = g * 128; c < g * 128 + 128; c++) {
        const float v = col[(size_t)c * L_SEQ];
        s += v; sq += v * v;
    }
    __shared__ float S1[4][64];
    __shared__ float S2[4][64];
    S1[g][pi] = s; S2[g][pi] = sq;
    __syncthreads();
    if (g == 0) {
        s  = S1[0][pi] + S1[1][pi] + S1[2][pi] + S1[3][pi];
        sq = S2[0][pi] + S2[1][pi] + S2[2][pi] + S2[3][pi];
        const float mu = s * (1.0f / CDIM);
        const float var = sq * (1.0f / CDIM) - mu * mu;
        S1[0][pi] = mu;
        S2[0][pi] = rsqrtf(var + 1e-5f);
    }
    __syncthreads();
    const float mu = S1[0][pi];
    const float rs = S2[0][pi];
    for (int c = g * 128; c < g * 128 + 128; c++) {
        const float v = col[(size_t)c * L_SEQ];
        col[(size_t)c * L_SEQ] = (v - mu) * rs * gamma[c] + beta[c];
    }
}

// ==================================================================
extern "C" void kernel_launch(void* const* d_in, const int* in_sizes, int n_in,
                              void* d_out, int out_size, void* d_ws, size_t ws_size,
                              hipStream_t stream) {
    const float* x    = (const float*)d_in[0];
    const int* mask   = (const int*)d_in[1];
    const float* pos  = (const float*)d_in[2];
    const float* Wq   = (const float*)d_in[3];
    const float* bq   = (const float*)d_in[4];
    const float* Wk   = (const float*)d_in[5];
    const float* bk   = (const float*)d_in[6];
    const float* Wv   = (const float*)d_in[7];
    const float* bv   = (const float*)d_in[8];
    const float* Wo   = (const float*)d_in[9];
    const float* bo   = (const float*)d_in[10];
    const float* rel  = (const float*)d_in[11];
    const float* gam  = (const float*)d_in[12];
    const float* bet  = (const float*)d_in[13];

    const size_t per = (size_t)2 * NHEADS * L_SEQ * HD;  // 2359296 elems
    ushort* qw = (ushort*)d_ws;
    ushort* kw = qw + per;
    ushort* vw = kw + per;
    float* attn = (float*)(vw + per);   // byte offset 14155776 (16B aligned)
    float* y    = (float*)d_out;

    dim3 g1(L_SEQ / 64, CDIM / 64, 2 * 3);
    qkv_gemm<<<g1, 256, 0, stream>>>(x, pos, Wq, bq, Wk, bk, Wv, bv, qw, kw, vw);

    flash_attn_mfma<<<dim3(576), 512, 0, stream>>>(qw, kw, vw, mask, rel, attn);

    dim3 g3(L_SEQ / 64, CDIM / 64, 2);
    out_gemm<<<g3, 256, 0, stream>>>(attn, Wo, bo, x, y);

    ln_kernel<<<(2 * L_SEQ) / 64, 256, 0, stream>>>(y, gam, bet);
}

// Round 2
// 498.612 us; speedup vs baseline: 1.0621x; 1.0621x over previous
//
#include <hip/hip_runtime.h>
#include <cstdint>

#define L_SEQ 2304
#define CDIM  512
#define NHEADS 8
#define HD    64
#define LL    ((size_t)L_SEQ * L_SEQ)
#define ROWS_TOT (16 * L_SEQ)   // 2 batches * 8 heads * L rows = 36864

typedef short  s8v  __attribute__((ext_vector_type(8)));
typedef float  f4v  __attribute__((ext_vector_type(4)));

__device__ __forceinline__ ushort f2bf(float f) {
    union { float f; uint32_t u; } v; v.f = f;
    uint32_t u = v.u;
    uint32_t r = (u + 0x7FFFu + ((u >> 16) & 1u)) >> 16;
    return (ushort)r;
}

// ==================================================================
// QKV projection -> bf16 outputs. q,k in (b,h,l,d); v transposed (b,h,d,l).
// Q pre-scaled by 0.125 (exact pow2). grid (36, 8, 6), block 256.
__global__ __launch_bounds__(256) void qkv_gemm(
    const float* __restrict__ x, const float* __restrict__ pos,
    const float* __restrict__ Wq, const float* __restrict__ bq,
    const float* __restrict__ Wk, const float* __restrict__ bk,
    const float* __restrict__ Wv, const float* __restrict__ bv,
    ushort* __restrict__ q_t, ushort* __restrict__ k_t, ushort* __restrict__ v_t)
{
    const int l0 = blockIdx.x * 64;
    const int o0 = blockIdx.y * 64;
    const int b  = blockIdx.z / 3;
    const int w  = blockIdx.z % 3;
    const float* W    = (w == 0) ? Wq : (w == 1) ? Wk : Wv;
    const float* bias = (w == 0) ? bq : (w == 1) ? bk : bv;

    __shared__ float As[16][68];
    __shared__ float Xs[16][68];

    const int t  = threadIdx.x;
    const int ti = t & 15;
    const int tj = t >> 4;
    float acc[4][4] = {};

    const float* xb = x + (size_t)b * CDIM * L_SEQ;

    for (int c0 = 0; c0 < CDIM; c0 += 16) {
        {
            const int oi = t >> 2;
            const int cc = (t & 3) * 4;
            const float4 wv = *(const float4*)&W[(size_t)(o0 + oi) * CDIM + c0 + cc];
            As[cc + 0][oi] = wv.x;
            As[cc + 1][oi] = wv.y;
            As[cc + 2][oi] = wv.z;
            As[cc + 3][oi] = wv.w;
        }
        {
            const int kk = t >> 4;
            const int j  = (t & 15) * 4;
            const size_t off = (size_t)(c0 + kk) * L_SEQ + l0 + j;
            float4 xv = *(const float4*)&xb[off];
            const float4 pv = *(const float4*)&pos[off];
            xv.x += pv.x; xv.y += pv.y; xv.z += pv.z; xv.w += pv.w;
            *(float4*)&Xs[kk][j] = xv;
        }
        __syncthreads();
        #pragma unroll
        for (int kk = 0; kk < 16; kk++) {
            const float4 a  = *(const float4*)&As[kk][ti * 4];
            const float4 bb = *(const float4*)&Xs[kk][tj * 4];
            const float av[4] = {a.x, a.y, a.z, a.w};
            const float bv4[4] = {bb.x, bb.y, bb.z, bb.w};
            #pragma unroll
            for (int i = 0; i < 4; i++)
                #pragma unroll
                for (int j = 0; j < 4; j++)
                    acc[i][j] += av[i] * bv4[j];
        }
        __syncthreads();
    }

    const int h = o0 >> 6;
    const float4 bi = *(const float4*)&bias[o0 + ti * 4];
    const float bia[4] = {bi.x, bi.y, bi.z, bi.w};

    if (w < 2) {
        // q/k row-major (b,h,l,d), Q scaled by 0.125
        const float sc = (w == 0) ? 0.125f : 1.0f;
        ushort* op = (w == 0 ? q_t : k_t) + ((size_t)b * NHEADS + h) * L_SEQ * HD;
        #pragma unroll
        for (int j = 0; j < 4; j++) {
            const int l = l0 + tj * 4 + j;
            ushort4 st;
            st.x = f2bf((acc[0][j] + bia[0]) * sc);
            st.y = f2bf((acc[1][j] + bia[1]) * sc);
            st.z = f2bf((acc[2][j] + bia[2]) * sc);
            st.w = f2bf((acc[3][j] + bia[3]) * sc);
            *(ushort4*)&op[(size_t)l * HD + ti * 4] = st;
        }
    } else {
        // v transposed (b,h,d,l)
        ushort* op = v_t + ((size_t)b * NHEADS + h) * HD * L_SEQ;
        #pragma unroll
        for (int i = 0; i < 4; i++) {
            const int d = ti * 4 + i;
            ushort4 st;
            st.x = f2bf(acc[i][0] + bia[i]);
            st.y = f2bf(acc[i][1] + bia[i]);
            st.z = f2bf(acc[i][2] + bia[i]);
            st.w = f2bf(acc[i][3] + bia[i]);
            *(ushort4*)&op[(size_t)d * L_SEQ + l0 + tj * 4] = st;
        }
    }
}

// ==================================================================
// MFMA flash attention, split-K ACROSS BLOCKS (flash-decoding).
// Block = 256 threads (4 waves), 64 q-rows of one (b,h), HALF the keys.
// half=0 -> keys [0,1152), half=1 -> keys [1152,2304). Each block writes
// unnormalized partial O plus per-row (m,l); combine_kernel merges.
// 1152 independent blocks -> 4.5 blocks/CU co-resident (LDS cap 6), i.e.
// twice the independent latency-hiding streams vs the 576-block version.
// grid 1152 (1D, XCD-pinned head), block 256.
__global__ __launch_bounds__(256) void flash_attn_mfma(
    const ushort* __restrict__ q, const ushort* __restrict__ k,
    const ushort* __restrict__ vt, const int* __restrict__ mask,
    const float* __restrict__ rel_table, float* __restrict__ Opart,
    float* __restrict__ Mpart, float* __restrict__ Lpart)
{
    __shared__ __align__(16) ushort Kf[512 * 8];   // B-frags for S
    __shared__ __align__(16) ushort Vf[512 * 8];   // B-frags for PV
    __shared__ __align__(16) ushort Pb[4 * 16 * 72]; // per-wave P, row-major [16][72]
    __shared__ float rt[65];

    const int t    = threadIdx.x;
    const int id   = blockIdx.x;
    const int h    = id & 7;            // XCD-pinned head
    const int s2   = id >> 3;           // [0,144)
    const int b    = s2 & 1;            // adjacent slots share mask rows (L2 reuse)
    const int half = (s2 >> 1) & 1;     // key half
    const int qb   = s2 >> 2;           // [0,36)
    const int bh   = b * NHEADS + h;
    const int l0   = qb * 64;
    const int w    = t >> 6;
    const int lane = t & 63;
    const int n16  = lane & 15;
    const int q4   = lane >> 4;

    if (t < 65) rt[t] = rel_table[h * 65 + t];

    const ushort* qp = q  + (size_t)bh * L_SEQ * HD;
    const ushort* kp = k  + (size_t)bh * L_SEQ * HD;
    const ushort* vp = vt + (size_t)bh * HD * L_SEQ;
    const int*    mp = mask + (size_t)h * LL;

    // Q A-fragments: A[m=lane&15][k=quad*8+j], rows l0+w*16+n16
    const int qrow = l0 + w * 16 + n16;
    const s8v qA0 = *(const s8v*)&qp[(size_t)qrow * HD + q4 * 8];
    const s8v qA1 = *(const s8v*)&qp[(size_t)qrow * HD + 32 + q4 * 8];

    f4v O[4] = {{0.f,0.f,0.f,0.f},{0.f,0.f,0.f,0.f},{0.f,0.f,0.f,0.f},{0.f,0.f,0.f,0.f}};
    float mrun[4] = {-3e38f, -3e38f, -3e38f, -3e38f};
    float lrun[4] = {0.f, 0.f, 0.f, 0.f};

    // precompute this thread's two staging chunk decodes (c = t, t+256)
    int sT[2], sS[2], sQ[2], sN[2];
    #pragma unroll
    for (int cc = 0; cc < 2; cc++) {
        const int c = t + cc * 256;
        const int g = c >> 6;
        sT[cc] = g >> 1; sS[cc] = g & 1;
        sQ[cc] = (c >> 4) & 3; sN[cc] = c & 15;
    }

    const int rowbase = l0 + w * 16 + q4 * 4;   // +r gives the C-layout row
    const int kbase = half * 1152;

    for (int mt = 0; mt < 18; mt++) {
        const int mb = kbase + mt * 64;
        __syncthreads();   // WAR: previous tile's reads done before restage
        #pragma unroll
        for (int cc = 0; cc < 2; cc++) {
            const int c = t + cc * 256;
            const int key = sT[cc] * 16 + sN[cc];
            const int d0  = sS[cc] * 32 + sQ[cc] * 8;
            *(s8v*)&Kf[c * 8] = *(const s8v*)&kp[(size_t)(mb + key) * HD + d0];
            // V chunk: element j = V[mb + d0+j][sT*16+sN] = vt[(sT*16+sN)][mb+d0+j]
            const int dd = sT[cc] * 16 + sN[cc];
            *(s8v*)&Vf[c * 8] = *(const s8v*)&vp[(size_t)dd * L_SEQ + mb + d0];
        }
        __syncthreads();

        // mask loads (issue early; int32 per harness bool convention)
        int mreg[4][4];
        #pragma unroll
        for (int t4 = 0; t4 < 4; t4++)
            #pragma unroll
            for (int r = 0; r < 4; r++)
                mreg[t4][r] = mp[(size_t)(rowbase + r) * L_SEQ + mb + t4 * 16 + n16];

        // S = Q K^T  (C layout: col=lane&15 -> key t4*16+n16, row=q4*4+r)
        f4v S[4];
        #pragma unroll
        for (int t4 = 0; t4 < 4; t4++) {
            const s8v b0 = *(const s8v*)&Kf[((t4 * 2 + 0) * 64 + lane) * 8];
            const s8v b1 = *(const s8v*)&Kf[((t4 * 2 + 1) * 64 + lane) * 8];
            f4v acc = {0.f, 0.f, 0.f, 0.f};
            acc = __builtin_amdgcn_mfma_f32_16x16x32_bf16(qA0, b0, acc, 0, 0, 0);
            acc = __builtin_amdgcn_mfma_f32_16x16x32_bf16(qA1, b1, acc, 0, 0, 0);
            S[t4] = acc;
        }

        // relative positional bias (then mask -> exactly -1e9, matching ref order)
        #pragma unroll
        for (int t4 = 0; t4 < 4; t4++) {
            const int A = (l0 + w * 16) - (mb + t4 * 16);
            if (A >= 47) {
                const float bu = rt[64];
                #pragma unroll
                for (int r = 0; r < 4; r++) S[t4][r] += bu;
            } else if (A <= -47) {
                const float bu = rt[0];
                #pragma unroll
                for (int r = 0; r < 4; r++) S[t4][r] += bu;
            } else {
                #pragma unroll
                for (int r = 0; r < 4; r++) {
                    int dix = A + q4 * 4 + r - n16;
                    dix = min(max(dix, -32), 32) + 32;
                    S[t4][r] += rt[dix];
                }
            }
            #pragma unroll
            for (int r = 0; r < 4; r++)
                if (mreg[t4][r] == 0) S[t4][r] = -1e9f;
        }

        // online softmax per row (row stats replicated over 16 lanes of quad)
        float mx[4];
        #pragma unroll
        for (int r = 0; r < 4; r++) {
            float m0 = fmaxf(fmaxf(S[0][r], S[1][r]), fmaxf(S[2][r], S[3][r]));
            m0 = fmaxf(m0, __shfl_xor(m0, 1));
            m0 = fmaxf(m0, __shfl_xor(m0, 2));
            m0 = fmaxf(m0, __shfl_xor(m0, 4));
            m0 = fmaxf(m0, __shfl_xor(m0, 8));
            mx[r] = m0;
        }
        float al[4];
        #pragma unroll
        for (int r = 0; r < 4; r++) {
            const float mn = fmaxf(mrun[r], mx[r]);
            al[r] = __expf(mrun[r] - mn);
            mrun[r] = mn;
            float sum = 0.f;
            #pragma unroll
            for (int t4 = 0; t4 < 4; t4++) {
                const float p = __expf(S[t4][r] - mn);
                S[t4][r] = p;
                sum += p;
                Pb[w * 1152 + (q4 * 4 + r) * 72 + t4 * 16 + n16] = f2bf(p);
            }
            sum += __shfl_xor(sum, 1);
            sum += __shfl_xor(sum, 2);
            sum += __shfl_xor(sum, 4);
            sum += __shfl_xor(sum, 8);
            lrun[r] = lrun[r] * al[r] + sum;
        }

        // rescale O, then O += P V   (per-wave Pb: same-wave dep, no barrier)
        const s8v pf0 = *(const s8v*)&Pb[w * 1152 + n16 * 72 + q4 * 8];
        const s8v pf1 = *(const s8v*)&Pb[w * 1152 + n16 * 72 + 32 + q4 * 8];
        #pragma unroll
        for (int t4 = 0; t4 < 4; t4++) {
            f4v o = O[t4];
            #pragma unroll
            for (int r = 0; r < 4; r++) o[r] *= al[r];
            const s8v v0 = *(const s8v*)&Vf[((t4 * 2 + 0) * 64 + lane) * 8];
            const s8v v1 = *(const s8v*)&Vf[((t4 * 2 + 1) * 64 + lane) * 8];
            o = __builtin_amdgcn_mfma_f32_16x16x32_bf16(pf0, v0, o, 0, 0, 0);
            o = __builtin_amdgcn_mfma_f32_16x16x32_bf16(pf1, v1, o, 0, 0, 0);
            O[t4] = o;
        }
    }

    // write UNNORMALIZED partial O + per-row stats for this key-half
    float* op = Opart + ((size_t)half * 16 + bh) * L_SEQ * HD;
    #pragma unroll
    for (int r = 0; r < 4; r++) {
        const size_t row = (size_t)(rowbase + r) * HD;
        #pragma unroll
        for (int t4 = 0; t4 < 4; t4++)
            op[row + t4 * 16 + n16] = O[t4][r];
    }
    if (n16 == 0) {
        const size_t sb = (size_t)half * ROWS_TOT + (size_t)bh * L_SEQ;
        #pragma unroll
        for (int r = 0; r < 4; r++) {
            Mpart[sb + rowbase + r] = mrun[r];
            Lpart[sb + rowbase + r] = lrun[r];
        }
    }
}

// ==================================================================
// Merge the two key-half partials. In-place: result lands in half 0 of O01.
// grid 2304, block 256 — one float4 per thread.
__global__ __launch_bounds__(256) void combine_kernel(
    float* __restrict__ O01, const float* __restrict__ Mp,
    const float* __restrict__ Lp)
{
    const int i   = blockIdx.x * 256 + threadIdx.x;  // float4 idx, 589824 total
    const int row = i >> 4;                          // bh*L + l
    const float m0 = Mp[row], m1 = Mp[ROWS_TOT + row];
    const float l0 = Lp[row], l1 = Lp[ROWS_TOT + row];
    const float M  = fmaxf(m0, m1);
    const float w0 = __expf(m0 - M);
    const float w1 = __expf(m1 - M);
    const float inv = 1.0f / (l0 * w0 + l1 * w1);
    const float f0 = w0 * inv;
    const float f1 = w1 * inv;
    float4 a = ((const float4*)O01)[i];
    const float4 c = ((const float4*)O01)[(size_t)ROWS_TOT * 16 + i];
    a.x = a.x * f0 + c.x * f1;
    a.y = a.y * f0 + c.y * f1;
    a.z = a.z * f0 + c.z * f1;
    a.w = a.w * f0 + c.w * f1;
    ((float4*)O01)[i] = a;
}

// ==================================================================
// Output projection + bias + residual (fp32). grid (36, 8, 2), block 256.
__global__ __launch_bounds__(256) void out_gemm(
    const float* __restrict__ attn, const float* __restrict__ Wo,
    const float* __restrict__ bo, const float* __restrict__ x,
    float* __restrict__ y)
{
    const int l0 = blockIdx.x * 64;
    const int o0 = blockIdx.y * 64;
    const int b  = blockIdx.z;

    __shared__ float As[16][68];
    __shared__ float Xs[16][68];

    const int t  = threadIdx.x;
    const int ti = t & 15;
    const int tj = t >> 4;
    float acc[4][4] = {};

    const float* ab = attn + (size_t)b * NHEADS * L_SEQ * HD;

    for (int c0 = 0; c0 < CDIM; c0 += 16) {
        {
            const int oi = t >> 2;
            const int cc = (t & 3) * 4;
            const float4 wv = *(const float4*)&Wo[(size_t)(o0 + oi) * CDIM + c0 + cc];
            As[cc + 0][oi] = wv.x;
            As[cc + 1][oi] = wv.y;
            As[cc + 2][oi] = wv.z;
            As[cc + 3][oi] = wv.w;
        }
        {
            const int j   = t & 63;
            const int kkb = (t >> 6) * 4;
            const int c   = c0 + kkb;
            const int hh  = c >> 6;
            const int dd  = c & 63;
            const float4 av = *(const float4*)&ab[((size_t)hh * L_SEQ + l0 + j) * HD + dd];
            Xs[kkb + 0][j] = av.x;
            Xs[kkb + 1][j] = av.y;
            Xs[kkb + 2][j] = av.z;
            Xs[kkb + 3][j] = av.w;
        }
        __syncthreads();
        #pragma unroll
        for (int kk = 0; kk < 16; kk++) {
            const float4 a  = *(const float4*)&As[kk][ti * 4];
            const float4 bb = *(const float4*)&Xs[kk][tj * 4];
            const float av[4] = {a.x, a.y, a.z, a.w};
            const float bv4[4] = {bb.x, bb.y, bb.z, bb.w};
            #pragma unroll
            for (int i = 0; i < 4; i++)
                #pragma unroll
                for (int j = 0; j < 4; j++)
                    acc[i][j] += av[i] * bv4[j];
        }
        __syncthreads();
    }

    const float4 bi = *(const float4*)&bo[o0 + ti * 4];
    const float bia[4] = {bi.x, bi.y, bi.z, bi.w};
    #pragma unroll
    for (int i = 0; i < 4; i++) {
        const int o = o0 + ti * 4 + i;
        const size_t off = ((size_t)b * CDIM + o) * L_SEQ + l0 + tj * 4;
        const float4 xv = *(const float4*)&x[off];
        float4 st;
        st.x = acc[i][0] + bia[i] + xv.x;
        st.y = acc[i][1] + bia[i] + xv.y;
        st.z = acc[i][2] + bia[i] + xv.z;
        st.w = acc[i][3] + bia[i] + xv.w;
        *(float4*)&y[off] = st;
    }
}

// ==================================================================
__global__ __launch_bounds__(256) void ln_kernel(
    float* __restrict__ y, const float* __restrict__ gamma,
    const float* __restrict__ beta)
{
    const int t  = threadIdx.x;
    const int pi = t & 63;
    const int g  = t >> 6;
    const int pos = blockIdx.x * 64 + pi;
    const int b = (pos >= L_SEQ) ? 1 : 0;
    const int l = pos - b * L_SEQ;
    float* col = y + (size_t)b * CDIM * L_SEQ + l;

    float s = 0.f, sq = 0.f;
    for (int c = g * 128; c < g * 128 + 128; c++) {
        const float v = col[(size_t)c * L_SEQ];
        s += v; sq += v * v;
    }
    __shared__ float S1[4][64];
    __shared__ float S2[4][64];
    S1[g][pi] = s; S2[g][pi] = sq;
    __syncthreads();
    if (g == 0) {
        s  = S1[0][pi] + S1[1][pi] + S1[2][pi] + S1[3][pi];
        sq = S2[0][pi] + S2[1][pi] + S2[2][pi] + S2[3][pi];
        const float mu = s * (1.0f / CDIM);
        const float var = sq * (1.0f / CDIM) - mu * mu;
        S1[0][pi] = mu;
        S2[0][pi] = rsqrtf(var + 1e-5f);
    }
    __syncthreads();
    const float mu = S1[0][pi];
    const float rs = S2[0][pi];
    for (int c = g * 128; c < g * 128 + 128; c++) {
        const float v = col[(size_t)c * L_SEQ];
        col[(size_t)c * L_SEQ] = (v - mu) * rs * gamma[c] + beta[c];
    }
}

// ==================================================================
extern "C" void kernel_launch(void* const* d_in, const int* in_sizes, int n_in,
                              void* d_out, int out_size, void* d_ws, size_t ws_size,
                              hipStream_t stream) {
    const float* x    = (const float*)d_in[0];
    const int* mask   = (const int*)d_in[1];
    const float* pos  = (const float*)d_in[2];
    const float* Wq   = (const float*)d_in[3];
    const float* bq   = (const float*)d_in[4];
    const float* Wk   = (const float*)d_in[5];
    const float* bk   = (const float*)d_in[6];
    const float* Wv   = (const float*)d_in[7];
    const float* bv   = (const float*)d_in[8];
    const float* Wo   = (const float*)d_in[9];
    const float* bo   = (const float*)d_in[10];
    const float* rel  = (const float*)d_in[11];
    const float* gam  = (const float*)d_in[12];
    const float* bet  = (const float*)d_in[13];

    const size_t per = (size_t)2 * NHEADS * L_SEQ * HD;  // 2359296 elems
    ushort* qw = (ushort*)d_ws;
    ushort* kw = qw + per;
    ushort* vw = kw + per;
    float* Opart = (float*)(vw + per);        // [2][16][L][64] fp32, 18.9 MB
    float* Mpart = Opart + 2 * per;           // [2][36864]
    float* Lpart = Mpart + 2 * ROWS_TOT;      // [2][36864]
    float* attn  = Opart;                     // combine merges in-place into half 0
    float* y     = (float*)d_out;

    dim3 g1(L_SEQ / 64, CDIM / 64, 2 * 3);
    qkv_gemm<<<g1, 256, 0, stream>>>(x, pos, Wq, bq, Wk, bk, Wv, bv, qw, kw, vw);

    flash_attn_mfma<<<dim3(1152), 256, 0, stream>>>(qw, kw, vw, mask, rel,
                                                    Opart, Mpart, Lpart);

    combine_kernel<<<dim3(2304), 256, 0, stream>>>(Opart, Mpart, Lpart);

    dim3 g3(L_SEQ / 64, CDIM / 64, 2);
    out_gemm<<<g3, 256, 0, stream>>>(attn, Wo, bo, x, y);

    ln_kernel<<<(2 * L_SEQ) / 64, 256, 0, stream>>>(y, gam, bet);
}